// Round 2
// baseline (355.549 us; speedup 1.0000x reference)
//
#include <hip/hip_runtime.h>

typedef __bf16 bf16;
typedef __attribute__((ext_vector_type(4))) float  f32x4;
typedef __attribute__((ext_vector_type(8))) short  s16x8;   // MFMA bf16 A/B fragment (guide-verified type)
typedef __attribute__((ext_vector_type(8))) __bf16 bf16x8;
typedef __attribute__((ext_vector_type(4))) __bf16 bf16x4;

#define MROWS 32768   // B*S
#define KD    576     // d_model = GEMM K
#define N1P   1792    // padded qkv cols (real 1728 = 576 q + 1152 kv)
#define N2P   640     // padded O-proj cols (real 576)

__device__ __forceinline__ void gload_lds16(const void* g, void* l) {
  __builtin_amdgcn_global_load_lds((const __attribute__((address_space(1))) void*)g,
                                   (__attribute__((address_space(3))) void*)l, 16, 0, 0);
}

// ---------------- RMSNorm: x (f32) -> xn (bf16) ----------------
// one wave per row; 576 f32 = 144 float4; lanes load 2-3 float4 each.
__global__ __launch_bounds__(256) void rmsnorm_k(const float* __restrict__ x,
                                                 bf16* __restrict__ xn) {
  const int lane = threadIdx.x & 63;
  const int row  = blockIdx.x * 4 + (threadIdx.x >> 6);
  const float4* xr = (const float4*)(x + (size_t)row * KD);
  float4 v0 = xr[lane];
  float4 v1 = xr[lane + 64];
  float4 v2 = {0.f, 0.f, 0.f, 0.f};
  if (lane < 16) v2 = xr[lane + 128];
  float ss = v0.x*v0.x + v0.y*v0.y + v0.z*v0.z + v0.w*v0.w
           + v1.x*v1.x + v1.y*v1.y + v1.z*v1.z + v1.w*v1.w
           + v2.x*v2.x + v2.y*v2.y + v2.z*v2.z + v2.w*v2.w;
#pragma unroll
  for (int off = 32; off > 0; off >>= 1) ss += __shfl_xor(ss, off, 64);
  const float inv = 1.0f / sqrtf(ss * (1.0f / 576.0f) + 1e-6f);
  bf16* orow = xn + (size_t)row * KD;
  bf16x4 o0 = {(bf16)(v0.x*inv), (bf16)(v0.y*inv), (bf16)(v0.z*inv), (bf16)(v0.w*inv)};
  *(bf16x4*)(orow + lane * 4) = o0;
  bf16x4 o1 = {(bf16)(v1.x*inv), (bf16)(v1.y*inv), (bf16)(v1.z*inv), (bf16)(v1.w*inv)};
  *(bf16x4*)(orow + (lane + 64) * 4) = o1;
  if (lane < 16) {
    bf16x4 o2 = {(bf16)(v2.x*inv), (bf16)(v2.y*inv), (bf16)(v2.z*inv), (bf16)(v2.w*inv)};
    *(bf16x4*)(orow + (lane + 128) * 4) = o2;
  }
}

// ---------------- RoPE cos/sin table: [2048][32] each (f32 path) ----------------
__global__ void rope_k(float* __restrict__ ctab, float* __restrict__ stab) {
  const int s = blockIdx.x * blockDim.x + threadIdx.x;
  if (s >= 2048) return;
#pragma unroll 1
  for (int i = 0; i < 32; ++i) {
    const float theta = powf(10000.0f, -(float)i * (1.0f / 32.0f));
    const float f = (float)s * theta;
    float sv, cv;
    sincosf(f, &sv, &cv);   // accurate-path sin/cos (proper range reduction)
    ctab[s * 32 + i] = cv;
    stab[s * 32 + i] = sv;
  }
}

// -------- weights -> bf16: Wcat = [Wq;Wkv] padded to 1792 rows; Wo padded to 640 --------
__global__ __launch_bounds__(256) void wconv_k(const float* __restrict__ Wq,
                                               const float* __restrict__ Wkv,
                                               const float* __restrict__ Wo,
                                               bf16* __restrict__ wcat,
                                               bf16* __restrict__ wo) {
  const int idx = blockIdx.x * 256 + threadIdx.x;   // grid covers 1792*576 exactly
  {
    const int row = idx / 576;
    float v = 0.f;
    if (row < 576)       v = Wq[idx];
    else if (row < 1728) v = Wkv[idx - 331776];
    wcat[idx] = (bf16)v;
  }
  if (idx < 640 * 576) {
    float v = (idx < 331776) ? Wo[idx] : 0.f;
    wo[idx] = (bf16)v;
  }
}

// ---------------- GEMM: C[m,n] = sum_k A[m,k]*Bw[n,k]  (both row-major, K=576) ----------------
// 128x128 tile, BK=64, 4 waves (2x2), mfma 16x16x32 bf16, global_load_lds w16,
// XOR-swizzled LDS (slot ^= row&7) via pre-swizzled global source (rule #21:
// linear dest + inverse-swz source + same-XOR read; XOR is the involution).
// EPI=0: store bf16 C (ldc cols). EPI=1: store f32 C (576 cols, masked) + identity add.
template <int EPI>
__global__ __launch_bounds__(256) void gemm_k(const bf16* __restrict__ A,
                                              const bf16* __restrict__ Bw,
                                              void* __restrict__ Cp,
                                              const float* __restrict__ ident,
                                              int ntiles, int ldc) {
  __shared__ bf16 As[128 * 64];
  __shared__ bf16 Bs[128 * 64];
  const int tid  = threadIdx.x;
  const int lane = tid & 63;
  // bijective XCD swizzle (gridDim.x % 8 == 0 for both calls)
  const int nwg = gridDim.x;
  const int cpx = nwg >> 3;
  const int swz = (blockIdx.x & 7) * cpx + (blockIdx.x >> 3);
  const int mt = swz / ntiles;
  const int nt = swz - mt * ntiles;
  const int wv = tid >> 6;
  const int wr = (wv >> 1) << 6;   // wave row offset in tile
  const int wc = (wv & 1) << 6;    // wave col offset in tile

  const size_t abase = (size_t)mt * 128 * KD;
  const size_t bbase = (size_t)nt * 128 * KD;

  f32x4 zero = {0.f, 0.f, 0.f, 0.f};
  f32x4 acc[4][4];
#pragma unroll
  for (int i = 0; i < 4; ++i)
#pragma unroll
    for (int j = 0; j < 4; ++j) acc[i][j] = zero;

  for (int kt = 0; kt < 9; ++kt) {
    const int k0 = kt * 64;
    __syncthreads();
#pragma unroll
    for (int r = 0; r < 4; ++r) {          // A tile: 1024 16B chunks / 256 thr
      const int c   = r * 256 + tid;
      const int row = c >> 3;
      const int ks  = (c & 7) ^ (row & 7); // fetch the chunk that BELONGS at phys slot c&7
      gload_lds16(A + abase + (size_t)row * KD + k0 + ks * 8, As + c * 8);
    }
#pragma unroll
    for (int r = 0; r < 4; ++r) {
      const int c   = r * 256 + tid;
      const int row = c >> 3;
      const int ks  = (c & 7) ^ (row & 7);
      gload_lds16(Bw + bbase + (size_t)row * KD + k0 + ks * 8, Bs + c * 8);
    }
    __syncthreads();                        // drains vmcnt(0): staged data visible
#pragma unroll
    for (int kk = 0; kk < 2; ++kk) {
      s16x8 af[4], bq[4];
#pragma unroll
      for (int i = 0; i < 4; ++i) {
        const int arow = wr + i * 16 + (lane & 15);
        const int aps  = ((kk << 2) + (lane >> 4)) ^ (arow & 7);
        af[i] = *(const s16x8*)(As + arow * 64 + aps * 8);
      }
#pragma unroll
      for (int j = 0; j < 4; ++j) {
        const int brow = wc + j * 16 + (lane & 15);
        const int bps  = ((kk << 2) + (lane >> 4)) ^ (brow & 7);
        bq[j] = *(const s16x8*)(Bs + brow * 64 + bps * 8);
      }
#pragma unroll
      for (int i = 0; i < 4; ++i)
#pragma unroll
        for (int j = 0; j < 4; ++j)
          acc[i][j] = __builtin_amdgcn_mfma_f32_16x16x32_bf16(af[i], bq[j], acc[i][j], 0, 0, 0);
    }
  }
  // epilogue: C/D layout col=lane&15, row=(lane>>4)*4+reg (m89-verified)
  const int rbase = mt * 128 + wr + ((lane >> 4) << 2);
  const int cbase = nt * 128 + wc + (lane & 15);
  if (EPI == 0) {
    bf16* C = (bf16*)Cp;
#pragma unroll
    for (int i = 0; i < 4; ++i)
#pragma unroll
      for (int j = 0; j < 4; ++j)
#pragma unroll
        for (int r = 0; r < 4; ++r)
          C[(size_t)(rbase + i * 16 + r) * ldc + (cbase + j * 16)] = (bf16)acc[i][j][r];
  } else {
    float* C = (float*)Cp;
#pragma unroll
    for (int i = 0; i < 4; ++i)
#pragma unroll
      for (int j = 0; j < 4; ++j) {
        const int col = cbase + j * 16;
        if (col < 576) {
#pragma unroll
          for (int r = 0; r < 4; ++r) {
            const size_t off = (size_t)(rbase + i * 16 + r) * 576 + col;
            C[off] = acc[i][j][r] + ident[off];
          }
        }
      }
  }
}

// ---------------- per-position head-mix attention ----------------
// one thread per (b,s,h): 9x9 scores over heads at this position, softmax, mix v.
// writes attn in [b][h][s][d] order => (B,H,S,D).reshape(B,S,576) is the flat
// buffer itself, so the O-proj A-matrix is contiguous (32768x576).
__global__ __launch_bounds__(256) void attn_k(const bf16* __restrict__ qkv,
                                              const float* __restrict__ ctab,
                                              const float* __restrict__ stab,
                                              bf16* __restrict__ attn) {
  const int tid = blockIdx.x * 256 + threadIdx.x;  // 0 .. 294911 exactly
  const int bs  = tid / 9;
  const int h   = tid - bs * 9;
  const int s   = bs & 2047;
  const bf16* qrow = qkv + (size_t)bs * N1P;

  float q[64];
#pragma unroll
  for (int c = 0; c < 8; ++c) {
    bf16x8 v = *(const bf16x8*)(qrow + h * 64 + c * 8);
#pragma unroll
    for (int e = 0; e < 8; ++e) q[c * 8 + e] = (float)v[e];
  }
  // RoPE (q only; reference does not rope k)
  const float* cr = ctab + s * 32;
  const float* sr = stab + s * 32;
#pragma unroll
  for (int i = 0; i < 32; ++i) {
    const float cv = cr[i], sv = sr[i];
    const float a = q[2 * i], b = q[2 * i + 1];
    q[2 * i]     = a * cv - b * sv;
    q[2 * i + 1] = a * sv + b * cv;
  }
  const bf16* kvr = qrow + 576;
  float sc[9];
#pragma unroll
  for (int g = 0; g < 9; ++g) {
    const bf16* kg = kvr + g * 128;
    float d0 = 0.f, d1 = 0.f, d2 = 0.f, d3 = 0.f;
#pragma unroll
    for (int c = 0; c < 8; ++c) {
      bf16x8 v = *(const bf16x8*)(kg + c * 8);
      d0 += q[c*8+0] * (float)v[0];
      d1 += q[c*8+1] * (float)v[1];
      d2 += q[c*8+2] * (float)v[2];
      d3 += q[c*8+3] * (float)v[3];
      d0 += q[c*8+4] * (float)v[4];
      d1 += q[c*8+5] * (float)v[5];
      d2 += q[c*8+6] * (float)v[6];
      d3 += q[c*8+7] * (float)v[7];
    }
    sc[g] = (d0 + d1 + d2 + d3) * 0.125f;   // 1/sqrt(64)
  }
  float mx = sc[0];
#pragma unroll
  for (int g = 1; g < 9; ++g) mx = fmaxf(mx, sc[g]);
  float sum = 0.f;
#pragma unroll
  for (int g = 0; g < 9; ++g) { sc[g] = expf(sc[g] - mx); sum += sc[g]; }
  const float inv = 1.0f / sum;

  float oacc[64];
#pragma unroll
  for (int e = 0; e < 64; ++e) oacc[e] = 0.f;
#pragma unroll
  for (int g = 0; g < 9; ++g) {
    const float w = sc[g] * inv;
    const bf16* vg = kvr + g * 128 + 64;
#pragma unroll
    for (int c = 0; c < 8; ++c) {
      bf16x8 v = *(const bf16x8*)(vg + c * 8);
#pragma unroll
      for (int e = 0; e < 8; ++e) oacc[c * 8 + e] += w * (float)v[e];
    }
  }
  const int b = bs >> 11;
  bf16* orow = attn + ((size_t)((b * 9 + h) * 2048 + s)) * 64;
#pragma unroll
  for (int c = 0; c < 8; ++c) {
    bf16x8 o;
#pragma unroll
    for (int e = 0; e < 8; ++e) o[e] = (bf16)oacc[c * 8 + e];
    *(bf16x8*)(orow + c * 8) = o;
  }
}

// ---------------- launch ----------------
extern "C" void kernel_launch(void* const* d_in, const int* in_sizes, int n_in,
                              void* d_out, int out_size, void* d_ws, size_t ws_size,
                              hipStream_t stream) {
  const float* x   = (const float*)d_in[0];
  const float* Wq  = (const float*)d_in[1];
  const float* Wkv = (const float*)d_in[2];
  const float* Wo  = (const float*)d_in[3];

  char* ws = (char*)d_ws;
  // ws layout (attn ALIASES xn: xn dead after GEMM1, attn_k runs after it on the
  // same stream). All offsets 256B-aligned.
  const size_t o_xn   = 0;                       // 32768*576*2   = 37,748,736 (xn, then attn)
  const size_t o_wcat = o_xn   + 37748736;       // 1792*576*2    =  2,064,384
  const size_t o_wo   = o_wcat + 2064384;        // 640*576*2     =    737,280
  const size_t o_ct   = o_wo   + 737280;         // 2048*32*4     =    262,144
  const size_t o_st   = o_ct   + 262144;         //                    262,144
  const size_t o_qkv  = o_st   + 262144;         // 32768*1792*2  = 117,440,512
  const size_t need   = o_qkv  + 117440512;      // ≈158.5 MB
  if (ws_size < need) return;                    // (diagnose via validation failure)

  bf16*  xn   = (bf16*)(ws + o_xn);
  bf16*  attn = (bf16*)(ws + o_xn);              // alias (see above)
  bf16*  wcat = (bf16*)(ws + o_wcat);
  bf16*  wo   = (bf16*)(ws + o_wo);
  float* ctab = (float*)(ws + o_ct);
  float* stab = (float*)(ws + o_st);
  bf16*  qkv  = (bf16*)(ws + o_qkv);

  rmsnorm_k<<<8192, 256, 0, stream>>>(x, xn);
  rope_k<<<32, 64, 0, stream>>>(ctab, stab);
  wconv_k<<<4032, 256, 0, stream>>>(Wq, Wkv, Wo, wcat, wo);
  // QKV: M=32768, N=1792(pad), K=576  -> grid 256*14
  gemm_k<0><<<3584, 256, 0, stream>>>(xn, wcat, (void*)qkv, nullptr, 14, N1P);
  attn_k<<<1152, 256, 0, stream>>>(qkv, ctab, stab, attn);
  // O-proj + identity: M=32768, N=640(pad, store-masked to 576), K=576 -> grid 256*5
  gemm_k<1><<<1280, 256, 0, stream>>>(attn, wo, d_out, x, 5, 576);
}